// Round 5
// baseline (304.356 us; speedup 1.0000x reference)
//
#include <hip/hip_runtime.h>
#include <hip/hip_bf16.h>

#define B_SIZE 4096
#define D_SIZE 256
#define N_SIZE 8192
#define NCHUNK 8
#define CHUNK 1024                 // cols per block
#define GROUP 64                   // cols per staged LDS group
#define NGROUPS (CHUNK / GROUP)    // 16
#define LOG2E10 14.4269504089f     // 10 * log2(e):  exp(10x) = exp2(x * LOG2E10)

typedef __attribute__((ext_vector_type(8))) short short8;
typedef __attribute__((ext_vector_type(4))) short short4v;
typedef __attribute__((ext_vector_type(4))) float floatx4;

// ws layout (bytes):
//       0 : float Sarr[2*8192]        (65536)   per-row full exp-sum (incl diag)
//   65536 : float g[3][128][256]      (393216)  per-class feature sums (S,T0,T1)
//  458752 : int   cnt[128]            (512)     label histogram
//  459264 : float lossAcc; int ticket (8)
//  524288 : bf16 featS |featT0|featT1 (3 x 2MB, contiguous)

__device__ __forceinline__ void async16(void* lds, const void* g) {
    __builtin_amdgcn_global_load_lds(
        (const __attribute__((address_space(1))) unsigned int*)g,
        (__attribute__((address_space(3))) unsigned int*)lds, 16, 0, 0);
}

// Normalize all 3 feature sets (12288 rows); first blocks zero the accumulators.
__global__ void norm_kernel(const float* __restrict__ hs,
                            const float* __restrict__ ht0,
                            const float* __restrict__ ht1,
                            __hip_bfloat16* __restrict__ dst,
                            float* __restrict__ zero_region) {
    int id  = blockIdx.x;
    int tid = threadIdx.x;
    int gid = id * 256 + tid;
    if (gid < 114818) zero_region[gid] = 0.0f;   // S + g + cnt + lossAcc + ticket

    const float* src = (id < 4096) ? (hs + id * D_SIZE)
                     : (id < 8192) ? (ht0 + (id - 4096) * D_SIZE)
                                   : (ht1 + (id - 8192) * D_SIZE);
    float x = src[tid];
    float ss = x * x;
#pragma unroll
    for (int off = 32; off > 0; off >>= 1) ss += __shfl_xor(ss, off);
    __shared__ float wsum[4];
    int wave = tid >> 6, lane = tid & 63;
    if (lane == 0) wsum[wave] = ss;
    __syncthreads();
    float tot = wsum[0] + wsum[1] + wsum[2] + wsum[3];
    float inv = 1.0f / fmaxf(sqrtf(tot), 1e-12f);
    dst[id * D_SIZE + tid] = __float2bfloat16(x * inv);
}

// Per-class feature sums g_c = sum_{lab_j=c} f_j, per feature set.
// 48 blocks x 256: block handles 256 rows of one set; 2 passes x 64 classes in LDS.
__global__ void gvec_kernel(const __hip_bfloat16* __restrict__ featBase,
                            const int* __restrict__ labels,
                            float* __restrict__ gOut,
                            int* __restrict__ cnt) {
    __shared__ float lg[64 * 256];   // 64 KB
    __shared__ int slab[256];
    const int b   = blockIdx.x;
    const int tid = threadIdx.x;
    const int set = b >> 4;
    const int rs0 = (b & 15) * 256;
    const __hip_bfloat16* f = featBase + set * B_SIZE * D_SIZE;
    float* gset = gOut + set * 32768;

    slab[tid] = labels[rs0 + tid] & 127;
    __syncthreads();
    if (set == 0) atomicAdd(&cnt[slab[tid]], 1);

    for (int pass = 0; pass < 2; ++pass) {
        for (int k = 0; k < 64; ++k) lg[k * 256 + tid] = 0.0f;
        __syncthreads();
        for (int it = 0; it < 256; ++it) {
            int lab = slab[it];
            if ((lab >> 6) == pass)
                lg[(lab & 63) * 256 + tid] += __bfloat162float(f[(rs0 + it) * D_SIZE + tid]);
        }
        __syncthreads();
        for (int k = 0; k < 64; ++k)
            atomicAdd(&gset[pass * 16384 + k * 256 + tid], lg[k * 256 + tid]);
        __syncthreads();
    }
}

// S-only sim kernel. grid (32 row-blocks of 256, 2 teachers, 8 col chunks), 256 thr.
// Wave owns 64 rows (4 row-tiles, A register-resident, full K=256). 64-col groups
// staged to LDS in EXACT MFMA-fragment order (slot = u*8192 + ks*1024 + lane*16) so
// every ds_read_b128 is lane-sequential (conflict-free) with immediate offsets.
// Epilogue is only S += exp2(acc * LOG2E10); diag/mask handled elsewhere.
__global__ __launch_bounds__(256, 2)
void sim_kernel(const __hip_bfloat16* __restrict__ featS,
                const __hip_bfloat16* __restrict__ featT0,
                const __hip_bfloat16* __restrict__ featT1,
                float* __restrict__ Sarr) {
    __shared__ __align__(16) unsigned char sB[2][32768];

    const int rb    = blockIdx.x;
    const int t     = blockIdx.y;
    const int chunk = blockIdx.z;
    const __hip_bfloat16* featT = t ? featT1 : featT0;

    const int tid  = threadIdx.x;
    const int w    = tid >> 6;
    const int l    = tid & 63;
    const int quad = l >> 4;
    const int lcol = l & 15;
    const int row_base = rb * 256 + w * 64;

    // A fragments: 4 row-tiles x 8 k-steps (128 VGPRs), one-time global load
    short8 af[4][8];
#pragma unroll
    for (int rt = 0; rt < 4; ++rt) {
        int arow = row_base + rt * 16 + lcol;
        const __hip_bfloat16* ap = (arow < B_SIZE) ? featS + arow * D_SIZE
                                                   : featT + (arow - B_SIZE) * D_SIZE;
#pragma unroll
        for (int ks = 0; ks < 8; ++ks)
            af[rt][ks] = *reinterpret_cast<const short8*>(ap + ks * 32 + quad * 8);
    }

    float Sp[4][4];
#pragma unroll
    for (int rt = 0; rt < 4; ++rt)
#pragma unroll
        for (int r = 0; r < 4; ++r) Sp[rt][r] = 0.0f;

    const int col0 = chunk * CHUNK;

    // Wave w stages col-tile u=w: lane l fetches col (l&15), k-bytes [(l>>4)*16 +ks*64)
    // -> lands at lds base + l*16, exactly the fragment order the compute reads.
    auto stage = [&](int b, int cb) {
        int tb = cb + w * 16;
        const __hip_bfloat16* cp = (tb < B_SIZE) ? featS + tb * D_SIZE
                                                 : featT + (tb - B_SIZE) * D_SIZE;
        const char* gp = (const char*)cp + (l & 15) * 512 + (l >> 4) * 16;
        unsigned char* lp = &sB[b][w * 8192];
#pragma unroll
        for (int ks = 0; ks < 8; ++ks)
            async16(lp + ks * 1024, gp + ks * 64);
    };

    stage(0, col0);

    for (int g = 0; g < NGROUPS; ++g) {
        const int buf = g & 1;
        __syncthreads();                                   // drains DMA for buf
        if (g + 1 < NGROUPS) stage(buf ^ 1, col0 + (g + 1) * GROUP);

#pragma unroll
        for (int up = 0; up < 2; ++up) {                   // u-pairs: limits acc VGPRs
            floatx4 acc[2][4];
#pragma unroll
            for (int j = 0; j < 2; ++j)
#pragma unroll
                for (int rt = 0; rt < 4; ++rt) acc[j][rt] = floatx4{0.f, 0.f, 0.f, 0.f};

#pragma unroll
            for (int ks = 0; ks < 8; ++ks) {
                short8 bf[2];
#pragma unroll
                for (int j = 0; j < 2; ++j)
                    bf[j] = *reinterpret_cast<const short8*>(
                        &sB[buf][(up * 2 + j) * 8192 + ks * 1024 + l * 16]);
#pragma unroll
                for (int j = 0; j < 2; ++j)
#pragma unroll
                    for (int rt = 0; rt < 4; ++rt)
                        acc[j][rt] = __builtin_amdgcn_mfma_f32_16x16x32_bf16(
                            af[rt][ks], bf[j], acc[j][rt], 0, 0, 0);
            }
#pragma unroll
            for (int j = 0; j < 2; ++j)
#pragma unroll
                for (int rt = 0; rt < 4; ++rt)
#pragma unroll
                    for (int r = 0; r < 4; ++r)
                        Sp[rt][r] += exp2f(acc[j][rt][r] * LOG2E10);
        }
    }

    // reduce over the 16 lanes (lcol) of each quad, then one atomic per row
#pragma unroll
    for (int rt = 0; rt < 4; ++rt)
#pragma unroll
        for (int r = 0; r < 4; ++r) {
#pragma unroll
            for (int m = 1; m < 16; m <<= 1) Sp[rt][r] += __shfl_xor(Sp[rt][r], m);
        }
    if (lcol == 0) {
#pragma unroll
        for (int rt = 0; rt < 4; ++rt)
#pragma unroll
            for (int r = 0; r < 4; ++r) {
                int row = row_base + rt * 16 + quad * 4 + r;
                atomicAdd(&Sarr[t * N_SIZE + row], Sp[rt][r]);
            }
    }
}

// Per-row stats + final loss. 64 blocks x 256 (one row per wave-iteration).
// P_i = log(S_i - exp(10*aii)) - 10*(f_i.g_lab - aii)/M;  out = sum P / 16384.
__global__ void rowstat_kernel(const __hip_bfloat16* __restrict__ featS,
                               const __hip_bfloat16* __restrict__ featT0,
                               const __hip_bfloat16* __restrict__ featT1,
                               const int* __restrict__ labels,
                               const float* __restrict__ gAll,
                               const int* __restrict__ cnt,
                               const float* __restrict__ Sarr,
                               float* __restrict__ lossAcc,
                               int* __restrict__ ticket,
                               float* __restrict__ out) {
    __shared__ float wpart[4];
    const int tid = threadIdx.x;
    const int wv  = tid >> 6;
    const int l   = tid & 63;
    const int waveid = blockIdx.x * 4 + wv;   // 0..255
    float psum = 0.0f;

    for (int it = 0; it < 64; ++it) {
        int R = waveid * 64 + it;             // 0..16383
        int t = R >> 13;
        int i = R & (N_SIZE - 1);
        const __hip_bfloat16* f = (i < B_SIZE) ? featS + i * D_SIZE
                                : (t ? featT1 : featT0) + (i - B_SIZE) * D_SIZE;
        int lab = labels[i & (B_SIZE - 1)] & 127;
        short4v fb = *reinterpret_cast<const short4v*>(f + l * 4);
        float fx[4];
#pragma unroll
        for (int k = 0; k < 4; ++k) {
            unsigned int u = ((unsigned int)(unsigned short)fb[k]) << 16;
            fx[k] = __uint_as_float(u);
        }
        const float* gS = gAll + lab * 256 + l * 4;
        const float* gT = gAll + (1 + t) * 32768 + lab * 256 + l * 4;
        float dot = 0.f, aii = 0.f;
#pragma unroll
        for (int k = 0; k < 4; ++k) {
            dot += fx[k] * (gS[k] + gT[k]);
            aii += fx[k] * fx[k];
        }
#pragma unroll
        for (int m = 1; m < 64; m <<= 1) {
            dot += __shfl_xor(dot, m);
            aii += __shfl_xor(aii, m);
        }
        if (l == 0) {
            float S = Sarr[t * N_SIZE + i];
            float M = 2.0f * (float)cnt[lab] - 1.0f;
            float E = exp2f(LOG2E10 * aii);
            psum += logf(S - E) - 10.0f * (dot - aii) / M;
        }
    }
    if (l == 0) wpart[wv] = psum;
    __syncthreads();
    if (tid == 0) {
        atomicAdd(lossAcc, wpart[0] + wpart[1] + wpart[2] + wpart[3]);
        __threadfence();
        if (atomicAdd(ticket, 1) == 63) {
            float tot = atomicAdd(lossAcc, 0.0f);   // atomic read-after-all-adds
            out[0] = tot / 16384.0f;
        }
    }
}

extern "C" void kernel_launch(void* const* d_in, const int* in_sizes, int n_in,
                              void* d_out, int out_size, void* d_ws, size_t ws_size,
                              hipStream_t stream) {
    const float* hs     = (const float*)d_in[0];
    const float* ht0    = (const float*)d_in[1];
    const float* ht1    = (const float*)d_in[2];
    const int*   labels = (const int*)d_in[3];

    char* ws = (char*)d_ws;
    float* Sarr    = (float*)(ws);
    float* gAll    = (float*)(ws + 65536);
    int*   cnt     = (int*)(ws + 458752);
    float* lossAcc = (float*)(ws + 459264);
    int*   ticket  = (int*)(ws + 459268);
    __hip_bfloat16* featS  = (__hip_bfloat16*)(ws + 524288);
    __hip_bfloat16* featT0 = (__hip_bfloat16*)(ws + 524288 + 2097152);
    __hip_bfloat16* featT1 = (__hip_bfloat16*)(ws + 524288 + 2 * 2097152);

    norm_kernel<<<3 * 4096, 256, 0, stream>>>(hs, ht0, ht1, featS, (float*)ws);
    gvec_kernel<<<48, 256, 0, stream>>>(featS, labels, gAll, cnt);
    sim_kernel<<<dim3(32, 2, NCHUNK), 256, 0, stream>>>(featS, featT0, featT1, Sarr);
    rowstat_kernel<<<64, 256, 0, stream>>>(featS, featT0, featT1, labels, gAll, cnt,
                                           Sarr, lossAcc, ticket, (float*)d_out);
}

// Round 6
// 186.685 us; speedup vs baseline: 1.6303x; 1.6303x over previous
//
#include <hip/hip_runtime.h>
#include <hip/hip_bf16.h>

#define B_SIZE 4096
#define D_SIZE 256
#define N_SIZE 8192
#define NCHUNK 8
#define CHUNK 1024                 // cols per block
#define GROUP 64                   // cols per staged LDS group
#define NGROUPS (CHUNK / GROUP)    // 16
#define LOG2E10 14.4269504089f     // 10 * log2(e):  exp(10x) = exp2(x * LOG2E10)

typedef __attribute__((ext_vector_type(8))) short short8;
typedef __attribute__((ext_vector_type(4))) short short4v;
typedef __attribute__((ext_vector_type(4))) float floatx4;

// ws layout (bytes):
//       0 : float Sarr[2*8192]        (65536)  per-row full exp-sum (incl diag)
//   65536 : float lossAcc; int ticket (8)
//   66048 : int cnt[128]              (512)
//   66560 : int off[128]              (512)
//   67072 : int idxS[4096]            (16384)  row indices bucketed by class
//   83968 : float g[3][128][256]      (393216) per-class feature sums
//  524288 : bf16 featS|featT0|featT1  (3 x 2MB contiguous)

__device__ __forceinline__ void async16(void* lds, const void* g) {
    __builtin_amdgcn_global_load_lds(
        (const __attribute__((address_space(1))) unsigned int*)g,
        (__attribute__((address_space(3))) unsigned int*)lds, 16, 0, 0);
}

// Normalize all 3 feature sets (12288 rows); first blocks zero Sarr+lossAcc+ticket.
__global__ void norm_kernel(const float* __restrict__ hs,
                            const float* __restrict__ ht0,
                            const float* __restrict__ ht1,
                            __hip_bfloat16* __restrict__ dst,
                            float* __restrict__ zero_region) {
    int id  = blockIdx.x;
    int tid = threadIdx.x;
    int gid = id * 256 + tid;
    if (gid < 16386) zero_region[gid] = 0.0f;   // Sarr + lossAcc + ticket

    const float* src = (id < 4096) ? (hs + id * D_SIZE)
                     : (id < 8192) ? (ht0 + (id - 4096) * D_SIZE)
                                   : (ht1 + (id - 8192) * D_SIZE);
    float x = src[tid];
    float ss = x * x;
#pragma unroll
    for (int off = 32; off > 0; off >>= 1) ss += __shfl_xor(ss, off);
    __shared__ float wsum[4];
    int wave = tid >> 6, lane = tid & 63;
    if (lane == 0) wsum[wave] = ss;
    __syncthreads();
    float tot = wsum[0] + wsum[1] + wsum[2] + wsum[3];
    float inv = 1.0f / fmaxf(sqrtf(tot), 1e-12f);
    dst[id * D_SIZE + tid] = __float2bfloat16(x * inv);
}

// 1 block: histogram, prefix, scatter row indices bucketed by class.
__global__ void scatter_kernel(const int* __restrict__ labels,
                               int* __restrict__ cnt, int* __restrict__ off,
                               int* __restrict__ idxS) {
    __shared__ int h[128], o[128], ctr[128];
    int tid = threadIdx.x;
    if (tid < 128) { h[tid] = 0; ctr[tid] = 0; }
    __syncthreads();
    for (int i = tid; i < B_SIZE; i += 256) atomicAdd(&h[labels[i] & 127], 1);
    __syncthreads();
    if (tid == 0) {
        int s = 0;
        for (int c = 0; c < 128; ++c) { o[c] = s; s += h[c]; }
    }
    __syncthreads();
    for (int i = tid; i < B_SIZE; i += 256) {
        int lab = labels[i] & 127;
        int pos = o[lab] + atomicAdd(&ctr[lab], 1);
        idxS[pos] = i;
    }
    if (tid < 128) { cnt[tid] = h[tid]; off[tid] = o[tid]; }
}

// g_c = sum_{lab_j=c} f_j per set. 384 blocks (set*128+c) x 256 threads.
// Register accumulate over the class's member rows; coalesced loads, no atomics.
__global__ void gvec_kernel(const __hip_bfloat16* __restrict__ featBase,
                            const int* __restrict__ cnt,
                            const int* __restrict__ off,
                            const int* __restrict__ idxS,
                            float* __restrict__ gOut) {
    const int c   = blockIdx.x & 127;
    const int set = blockIdx.x >> 7;
    const int tid = threadIdx.x;
    const __hip_bfloat16* f = featBase + set * B_SIZE * D_SIZE;
    __shared__ int sIdx[256];
    const int n = cnt[c], o = off[c];
    float acc = 0.0f;
    for (int base = 0; base < n; base += 256) {
        int m = n - base; if (m > 256) m = 256;
        __syncthreads();
        if (tid < m) sIdx[tid] = idxS[o + base + tid];
        __syncthreads();
        for (int k = 0; k < m; ++k)
            acc += __bfloat162float(f[sIdx[k] * D_SIZE + tid]);
    }
    gOut[set * 32768 + c * 256 + tid] = acc;
}

// S-only sim kernel (unchanged from R5): grid (32,2,8), 256 thr, wave owns 64 rows,
// LDS staged in exact MFMA-fragment order, epilogue = exp2 accumulate only.
__global__ __launch_bounds__(256, 2)
void sim_kernel(const __hip_bfloat16* __restrict__ featS,
                const __hip_bfloat16* __restrict__ featT0,
                const __hip_bfloat16* __restrict__ featT1,
                float* __restrict__ Sarr) {
    __shared__ __align__(16) unsigned char sB[2][32768];

    const int rb    = blockIdx.x;
    const int t     = blockIdx.y;
    const int chunk = blockIdx.z;
    const __hip_bfloat16* featT = t ? featT1 : featT0;

    const int tid  = threadIdx.x;
    const int w    = tid >> 6;
    const int l    = tid & 63;
    const int quad = l >> 4;
    const int lcol = l & 15;
    const int row_base = rb * 256 + w * 64;

    short8 af[4][8];
#pragma unroll
    for (int rt = 0; rt < 4; ++rt) {
        int arow = row_base + rt * 16 + lcol;
        const __hip_bfloat16* ap = (arow < B_SIZE) ? featS + arow * D_SIZE
                                                   : featT + (arow - B_SIZE) * D_SIZE;
#pragma unroll
        for (int ks = 0; ks < 8; ++ks)
            af[rt][ks] = *reinterpret_cast<const short8*>(ap + ks * 32 + quad * 8);
    }

    float Sp[4][4];
#pragma unroll
    for (int rt = 0; rt < 4; ++rt)
#pragma unroll
        for (int r = 0; r < 4; ++r) Sp[rt][r] = 0.0f;

    const int col0 = chunk * CHUNK;

    auto stage = [&](int b, int cb) {
        int tb = cb + w * 16;
        const __hip_bfloat16* cp = (tb < B_SIZE) ? featS + tb * D_SIZE
                                                 : featT + (tb - B_SIZE) * D_SIZE;
        const char* gp = (const char*)cp + (l & 15) * 512 + (l >> 4) * 16;
        unsigned char* lp = &sB[b][w * 8192];
#pragma unroll
        for (int ks = 0; ks < 8; ++ks)
            async16(lp + ks * 1024, gp + ks * 64);
    };

    stage(0, col0);

    for (int g = 0; g < NGROUPS; ++g) {
        const int buf = g & 1;
        __syncthreads();
        if (g + 1 < NGROUPS) stage(buf ^ 1, col0 + (g + 1) * GROUP);

#pragma unroll
        for (int up = 0; up < 2; ++up) {
            floatx4 acc[2][4];
#pragma unroll
            for (int j = 0; j < 2; ++j)
#pragma unroll
                for (int rt = 0; rt < 4; ++rt) acc[j][rt] = floatx4{0.f, 0.f, 0.f, 0.f};

#pragma unroll
            for (int ks = 0; ks < 8; ++ks) {
                short8 bf[2];
#pragma unroll
                for (int j = 0; j < 2; ++j)
                    bf[j] = *reinterpret_cast<const short8*>(
                        &sB[buf][(up * 2 + j) * 8192 + ks * 1024 + l * 16]);
#pragma unroll
                for (int j = 0; j < 2; ++j)
#pragma unroll
                    for (int rt = 0; rt < 4; ++rt)
                        acc[j][rt] = __builtin_amdgcn_mfma_f32_16x16x32_bf16(
                            af[rt][ks], bf[j], acc[j][rt], 0, 0, 0);
            }
#pragma unroll
            for (int j = 0; j < 2; ++j)
#pragma unroll
                for (int rt = 0; rt < 4; ++rt)
#pragma unroll
                    for (int r = 0; r < 4; ++r)
                        Sp[rt][r] += exp2f(acc[j][rt][r] * LOG2E10);
        }
    }

#pragma unroll
    for (int rt = 0; rt < 4; ++rt)
#pragma unroll
        for (int r = 0; r < 4; ++r) {
#pragma unroll
            for (int m = 1; m < 16; m <<= 1) Sp[rt][r] += __shfl_xor(Sp[rt][r], m);
        }
    if (lcol == 0) {
#pragma unroll
        for (int rt = 0; rt < 4; ++rt)
#pragma unroll
            for (int r = 0; r < 4; ++r) {
                int row = row_base + rt * 16 + quad * 4 + r;
                atomicAdd(&Sarr[t * N_SIZE + row], Sp[rt][r]);
            }
    }
}

// Per-row stats + final loss. 256 blocks x 256; wave handles 16 rows.
__global__ void rowstat_kernel(const __hip_bfloat16* __restrict__ featS,
                               const __hip_bfloat16* __restrict__ featT0,
                               const __hip_bfloat16* __restrict__ featT1,
                               const int* __restrict__ labels,
                               const float* __restrict__ gAll,
                               const int* __restrict__ cnt,
                               const float* __restrict__ Sarr,
                               float* __restrict__ lossAcc,
                               int* __restrict__ ticket,
                               float* __restrict__ out) {
    __shared__ float wpart[4];
    const int tid = threadIdx.x;
    const int wv  = tid >> 6;
    const int l   = tid & 63;
    const int waveid = blockIdx.x * 4 + wv;   // 0..1023
    float psum = 0.0f;

    for (int it = 0; it < 16; ++it) {
        int R = waveid * 16 + it;             // 0..16383
        int t = R >> 13;
        int i = R & (N_SIZE - 1);
        const __hip_bfloat16* f = (i < B_SIZE) ? featS + i * D_SIZE
                                : (t ? featT1 : featT0) + (i - B_SIZE) * D_SIZE;
        int lab = labels[i & (B_SIZE - 1)] & 127;
        short4v fb = *reinterpret_cast<const short4v*>(f + l * 4);
        float fx[4];
#pragma unroll
        for (int k = 0; k < 4; ++k) {
            unsigned int u = ((unsigned int)(unsigned short)fb[k]) << 16;
            fx[k] = __uint_as_float(u);
        }
        const float* gS = gAll + lab * 256 + l * 4;
        const float* gT = gAll + (1 + t) * 32768 + lab * 256 + l * 4;
        float dot = 0.f, aii = 0.f;
#pragma unroll
        for (int k = 0; k < 4; ++k) {
            dot += fx[k] * (gS[k] + gT[k]);
            aii += fx[k] * fx[k];
        }
#pragma unroll
        for (int m = 1; m < 64; m <<= 1) {
            dot += __shfl_xor(dot, m);
            aii += __shfl_xor(aii, m);
        }
        if (l == 0) {
            float S = Sarr[t * N_SIZE + i];
            float M = 2.0f * (float)cnt[lab] - 1.0f;
            float E = exp2f(LOG2E10 * aii);
            psum += logf(S - E) - 10.0f * (dot - aii) / M;
        }
    }
    if (l == 0) wpart[wv] = psum;
    __syncthreads();
    if (tid == 0) {
        atomicAdd(lossAcc, wpart[0] + wpart[1] + wpart[2] + wpart[3]);
        __threadfence();
        if (atomicAdd(ticket, 1) == 255) {
            float tot = atomicAdd(lossAcc, 0.0f);
            out[0] = tot / 16384.0f;
        }
    }
}

extern "C" void kernel_launch(void* const* d_in, const int* in_sizes, int n_in,
                              void* d_out, int out_size, void* d_ws, size_t ws_size,
                              hipStream_t stream) {
    const float* hs     = (const float*)d_in[0];
    const float* ht0    = (const float*)d_in[1];
    const float* ht1    = (const float*)d_in[2];
    const int*   labels = (const int*)d_in[3];

    char* ws = (char*)d_ws;
    float* Sarr    = (float*)(ws);
    float* lossAcc = (float*)(ws + 65536);
    int*   ticket  = (int*)(ws + 65540);
    int*   cnt     = (int*)(ws + 66048);
    int*   offv    = (int*)(ws + 66560);
    int*   idxS    = (int*)(ws + 67072);
    float* gAll    = (float*)(ws + 83968);
    __hip_bfloat16* featS  = (__hip_bfloat16*)(ws + 524288);
    __hip_bfloat16* featT0 = (__hip_bfloat16*)(ws + 524288 + 2097152);
    __hip_bfloat16* featT1 = (__hip_bfloat16*)(ws + 524288 + 2 * 2097152);

    norm_kernel<<<3 * 4096, 256, 0, stream>>>(hs, ht0, ht1, featS, (float*)ws);
    scatter_kernel<<<1, 256, 0, stream>>>(labels, cnt, offv, idxS);
    gvec_kernel<<<384, 256, 0, stream>>>(featS, cnt, offv, idxS, gAll);
    sim_kernel<<<dim3(32, 2, NCHUNK), 256, 0, stream>>>(featS, featT0, featT1, Sarr);
    rowstat_kernel<<<256, 256, 0, stream>>>(featS, featT0, featT1, labels, gAll, cnt,
                                            Sarr, lossAcc, ticket, (float*)d_out);
}

// Round 7
// 165.795 us; speedup vs baseline: 1.8357x; 1.1260x over previous
//
#include <hip/hip_runtime.h>
#include <hip/hip_bf16.h>

#define B_SIZE 4096
#define D_SIZE 256
#define N_SIZE 8192
#define LOG2E10 14.4269504089f     // 10 * log2(e):  exp(10x) = exp2(x * LOG2E10)

typedef __attribute__((ext_vector_type(8))) short short8;
typedef __attribute__((ext_vector_type(4))) short short4v;
typedef __attribute__((ext_vector_type(4))) float floatx4;

// ws layout (bytes):
//       0 : float Sarr[2*8192]        (65536)  per-row full exp-sum (incl diag)
//   65536 : float lossAcc; int ticket (8)
//   66048 : int cnt[128]              (512)
//   66560 : int off[128]              (512)
//   67072 : int idxS[4096]            (16384)  row indices bucketed by class
//   83968 : float g[3][128][256]      (393216) per-class feature sums
//  524288 : bf16 featS|featT0|featT1  (3 x 2MB contiguous)

__device__ __forceinline__ void async16(void* lds, const void* g) {
    __builtin_amdgcn_global_load_lds(
        (const __attribute__((address_space(1))) unsigned int*)g,
        (__attribute__((address_space(3))) unsigned int*)lds, 16, 0, 0);
}

// Normalize all 3 feature sets; first blocks zero Sarr+lossAcc+ticket;
// block 0 additionally does the label histogram/prefix/scatter.
__global__ void norm_kernel(const float* __restrict__ hs,
                            const float* __restrict__ ht0,
                            const float* __restrict__ ht1,
                            __hip_bfloat16* __restrict__ dst,
                            float* __restrict__ zero_region,
                            const int* __restrict__ labels,
                            int* __restrict__ cnt, int* __restrict__ offv,
                            int* __restrict__ idxS) {
    int id  = blockIdx.x;
    int tid = threadIdx.x;
    int gid = id * 256 + tid;
    if (gid < 16386) zero_region[gid] = 0.0f;   // Sarr + lossAcc + ticket

    const float* src = (id < 4096) ? (hs + id * D_SIZE)
                     : (id < 8192) ? (ht0 + (id - 4096) * D_SIZE)
                                   : (ht1 + (id - 8192) * D_SIZE);
    float x = src[tid];
    float ss = x * x;
#pragma unroll
    for (int off = 32; off > 0; off >>= 1) ss += __shfl_xor(ss, off);
    __shared__ float wsum[4];
    int wave = tid >> 6, lane = tid & 63;
    if (lane == 0) wsum[wave] = ss;
    __syncthreads();
    float tot = wsum[0] + wsum[1] + wsum[2] + wsum[3];
    float inv = 1.0f / fmaxf(sqrtf(tot), 1e-12f);
    dst[id * D_SIZE + tid] = __float2bfloat16(x * inv);

    if (id == 0) {   // fused scatter (histogram + prefix + bucket indices)
        __shared__ int h[128], o[128], ctr[128];
        if (tid < 128) { h[tid] = 0; ctr[tid] = 0; }
        __syncthreads();
        for (int i = tid; i < B_SIZE; i += 256) atomicAdd(&h[labels[i] & 127], 1);
        __syncthreads();
        if (tid == 0) {
            int s = 0;
            for (int c = 0; c < 128; ++c) { o[c] = s; s += h[c]; }
        }
        __syncthreads();
        for (int i = tid; i < B_SIZE; i += 256) {
            int lab = labels[i] & 127;
            int pos = o[lab] + atomicAdd(&ctr[lab], 1);
            idxS[pos] = i;
        }
        if (tid < 128) { cnt[tid] = h[tid]; offv[tid] = o[tid]; }
    }
}

// g_c = sum_{lab_j=c} f_j per set. 384 blocks (set*128+c) x 256 threads.
__global__ void gvec_kernel(const __hip_bfloat16* __restrict__ featBase,
                            const int* __restrict__ cnt,
                            const int* __restrict__ off,
                            const int* __restrict__ idxS,
                            float* __restrict__ gOut) {
    const int c   = blockIdx.x & 127;
    const int set = blockIdx.x >> 7;
    const int tid = threadIdx.x;
    const __hip_bfloat16* f = featBase + set * B_SIZE * D_SIZE;
    __shared__ int sIdx[256];
    const int n = cnt[c], o = off[c];
    float acc = 0.0f;
    for (int base = 0; base < n; base += 256) {
        int m = n - base; if (m > 256) m = 256;
        __syncthreads();
        if (tid < m) sIdx[tid] = idxS[o + base + tid];
        __syncthreads();
        for (int k = 0; k < m; ++k)
            acc += __bfloat162float(f[sIdx[k] * D_SIZE + tid]);
    }
    gOut[set * 32768 + c * 256 + tid] = acc;
}

// Symmetric S-only sim kernel. grid (528 lower-tri (R,C) pairs, 2 teachers).
// Block: rows [256R,256R+256), 4 waves x 64 rows; cols [256C,256C+256) in 4
// 64-col LDS-staged groups (dbuf, MFMA-fragment order, conflict-free).
// Per wave, a 64-col group is: below-diag (row+col sums via symmetry),
// diagonal (row sums only), or above-diag (skipped).
__global__ __launch_bounds__(256, 2)
void sim_kernel(const __hip_bfloat16* __restrict__ featS,
                const __hip_bfloat16* __restrict__ featT0,
                const __hip_bfloat16* __restrict__ featT1,
                float* __restrict__ Sarr) {
    __shared__ __align__(16) unsigned char sB[2][32768];

    const int p = blockIdx.x;   // triangular pair index
    const int t = blockIdx.y;
    const __hip_bfloat16* featT = t ? featT1 : featT0;

    int R = (int)((sqrtf((float)(8 * p + 1)) - 1.0f) * 0.5f);
    while ((R + 1) * (R + 2) / 2 <= p) ++R;
    while (R * (R + 1) / 2 > p) --R;
    const int C = p - R * (R + 1) / 2;

    const int tid  = threadIdx.x;
    const int w    = tid >> 6;
    const int l    = tid & 63;
    const int quad = l >> 4;
    const int lcol = l & 15;
    const int row_base = R * 256 + w * 64;

    // A fragments: 4 row-tiles x 8 k-steps, register resident
    short8 af[4][8];
#pragma unroll
    for (int rt = 0; rt < 4; ++rt) {
        int arow = row_base + rt * 16 + lcol;
        const __hip_bfloat16* ap = (arow < B_SIZE) ? featS + arow * D_SIZE
                                                   : featT + (arow - B_SIZE) * D_SIZE;
#pragma unroll
        for (int ks = 0; ks < 8; ++ks)
            af[rt][ks] = *reinterpret_cast<const short8*>(ap + ks * 32 + quad * 8);
    }

    float Sp[4][4];
#pragma unroll
    for (int rt = 0; rt < 4; ++rt)
#pragma unroll
        for (int r = 0; r < 4; ++r) Sp[rt][r] = 0.0f;

    const int col0 = C * 256;

    auto stage = [&](int b, int cb) {
        int tb = cb + w * 16;
        const __hip_bfloat16* cp = (tb < B_SIZE) ? featS + tb * D_SIZE
                                                 : featT + (tb - B_SIZE) * D_SIZE;
        const char* gp = (const char*)cp + (l & 15) * 512 + (l >> 4) * 16;
        unsigned char* lp = &sB[b][w * 8192];
#pragma unroll
        for (int ks = 0; ks < 8; ++ks)
            async16(lp + ks * 1024, gp + ks * 64);
    };

    stage(0, col0);

    for (int g = 0; g < 4; ++g) {
        const int buf = g & 1;
        __syncthreads();                               // drains DMA for buf
        if (g + 1 < 4) stage(buf ^ 1, col0 + (g + 1) * 64);

        const int gcol = col0 + g * 64;
        if (gcol > row_base) continue;                 // above diagonal: skip
        const bool diag = (gcol == row_base);

        float Cp[4] = {0.f, 0.f, 0.f, 0.f};           // per-col partial sums
#pragma unroll
        for (int up = 0; up < 2; ++up) {
            floatx4 acc[2][4];
#pragma unroll
            for (int j = 0; j < 2; ++j)
#pragma unroll
                for (int rt = 0; rt < 4; ++rt) acc[j][rt] = floatx4{0.f, 0.f, 0.f, 0.f};

#pragma unroll
            for (int ks = 0; ks < 8; ++ks) {
                short8 bf[2];
#pragma unroll
                for (int j = 0; j < 2; ++j)
                    bf[j] = *reinterpret_cast<const short8*>(
                        &sB[buf][(up * 2 + j) * 8192 + ks * 1024 + l * 16]);
#pragma unroll
                for (int j = 0; j < 2; ++j)
#pragma unroll
                    for (int rt = 0; rt < 4; ++rt)
                        acc[j][rt] = __builtin_amdgcn_mfma_f32_16x16x32_bf16(
                            af[rt][ks], bf[j], acc[j][rt], 0, 0, 0);
            }
#pragma unroll
            for (int j = 0; j < 2; ++j)
#pragma unroll
                for (int rt = 0; rt < 4; ++rt)
#pragma unroll
                    for (int r = 0; r < 4; ++r) {
                        float e = exp2f(acc[j][rt][r] * LOG2E10);
                        Sp[rt][r] += e;
                        Cp[up * 2 + j] += e;
                    }
        }

        if (!diag) {   // symmetric contribution: col j gets e_ij summed over rows
#pragma unroll
            for (int u = 0; u < 4; ++u) {
                Cp[u] += __shfl_xor(Cp[u], 16);
                Cp[u] += __shfl_xor(Cp[u], 32);
            }
            if (quad == 0) {
#pragma unroll
                for (int u = 0; u < 4; ++u)
                    atomicAdd(&Sarr[t * N_SIZE + gcol + u * 16 + lcol], Cp[u]);
            }
        }
    }

    // row-sum flush: reduce over the 16 col-lanes of each quad
#pragma unroll
    for (int rt = 0; rt < 4; ++rt)
#pragma unroll
        for (int r = 0; r < 4; ++r) {
#pragma unroll
            for (int m = 1; m < 16; m <<= 1) Sp[rt][r] += __shfl_xor(Sp[rt][r], m);
        }
    if (lcol == 0) {
#pragma unroll
        for (int rt = 0; rt < 4; ++rt)
#pragma unroll
            for (int r = 0; r < 4; ++r) {
                int row = row_base + rt * 16 + quad * 4 + r;
                atomicAdd(&Sarr[t * N_SIZE + row], Sp[rt][r]);
            }
    }
}

// Per-row stats + final loss. 512 blocks x 256; wave handles 8 rows.
__global__ void rowstat_kernel(const __hip_bfloat16* __restrict__ featS,
                               const __hip_bfloat16* __restrict__ featT0,
                               const __hip_bfloat16* __restrict__ featT1,
                               const int* __restrict__ labels,
                               const float* __restrict__ gAll,
                               const int* __restrict__ cnt,
                               const float* __restrict__ Sarr,
                               float* __restrict__ lossAcc,
                               int* __restrict__ ticket,
                               float* __restrict__ out) {
    __shared__ float wpart[4];
    const int tid = threadIdx.x;
    const int wv  = tid >> 6;
    const int l   = tid & 63;
    const int waveid = blockIdx.x * 4 + wv;   // 0..2047
    float psum = 0.0f;

    for (int it = 0; it < 8; ++it) {
        int R = waveid * 8 + it;              // 0..16383
        int t = R >> 13;
        int i = R & (N_SIZE - 1);
        const __hip_bfloat16* f = (i < B_SIZE) ? featS + i * D_SIZE
                                : (t ? featT1 : featT0) + (i - B_SIZE) * D_SIZE;
        int lab = labels[i & (B_SIZE - 1)] & 127;
        short4v fb = *reinterpret_cast<const short4v*>(f + l * 4);
        float fx[4];
#pragma unroll
        for (int k = 0; k < 4; ++k) {
            unsigned int u = ((unsigned int)(unsigned short)fb[k]) << 16;
            fx[k] = __uint_as_float(u);
        }
        const float* gS = gAll + lab * 256 + l * 4;
        const float* gT = gAll + (1 + t) * 32768 + lab * 256 + l * 4;
        float dot = 0.f, aii = 0.f;
#pragma unroll
        for (int k = 0; k < 4; ++k) {
            dot += fx[k] * (gS[k] + gT[k]);
            aii += fx[k] * fx[k];
        }
#pragma unroll
        for (int m = 1; m < 64; m <<= 1) {
            dot += __shfl_xor(dot, m);
            aii += __shfl_xor(aii, m);
        }
        if (l == 0) {
            float S = Sarr[t * N_SIZE + i];
            float M = 2.0f * (float)cnt[lab] - 1.0f;
            float E = exp2f(LOG2E10 * aii);
            psum += logf(S - E) - 10.0f * (dot - aii) / M;
        }
    }
    if (l == 0) wpart[wv] = psum;
    __syncthreads();
    if (tid == 0) {
        atomicAdd(lossAcc, wpart[0] + wpart[1] + wpart[2] + wpart[3]);
        __threadfence();
        if (atomicAdd(ticket, 1) == 511) {
            float tot = atomicAdd(lossAcc, 0.0f);
            out[0] = tot / 16384.0f;
        }
    }
}

extern "C" void kernel_launch(void* const* d_in, const int* in_sizes, int n_in,
                              void* d_out, int out_size, void* d_ws, size_t ws_size,
                              hipStream_t stream) {
    const float* hs     = (const float*)d_in[0];
    const float* ht0    = (const float*)d_in[1];
    const float* ht1    = (const float*)d_in[2];
    const int*   labels = (const int*)d_in[3];

    char* ws = (char*)d_ws;
    float* Sarr    = (float*)(ws);
    float* lossAcc = (float*)(ws + 65536);
    int*   ticket  = (int*)(ws + 65540);
    int*   cnt     = (int*)(ws + 66048);
    int*   offv    = (int*)(ws + 66560);
    int*   idxS    = (int*)(ws + 67072);
    float* gAll    = (float*)(ws + 83968);
    __hip_bfloat16* featS  = (__hip_bfloat16*)(ws + 524288);
    __hip_bfloat16* featT0 = (__hip_bfloat16*)(ws + 524288 + 2097152);
    __hip_bfloat16* featT1 = (__hip_bfloat16*)(ws + 524288 + 2 * 2097152);

    norm_kernel<<<3 * 4096, 256, 0, stream>>>(hs, ht0, ht1, featS, (float*)ws,
                                              labels, cnt, offv, idxS);
    gvec_kernel<<<384, 256, 0, stream>>>(featS, cnt, offv, idxS, gAll);
    sim_kernel<<<dim3(528, 2), 256, 0, stream>>>(featS, featT0, featT1, Sarr);
    rowstat_kernel<<<512, 256, 0, stream>>>(featS, featT0, featT1, labels, gAll, cnt,
                                            Sarr, lossAcc, ticket, (float*)d_out);
}